// Round 3
// baseline (85.145 us; speedup 1.0000x reference)
//
#include <hip/hip_runtime.h>

#define N_CAMP 50
#define DAYS   365
#define ROW    366          // DAYS+1
#define BASIS  1e-10f
#define BATCH  4096
#define B_PER_BLK 4
#define THR_PER_B 96        // 92 active quads (ceil(365/4)), 4 spare
#define NTHR   (B_PER_BLK * THR_PER_B)   // 384

// Each thread handles 4 consecutive days of one batch element, loading one
// float4 of adstock per campaign (16 B/lane -> dwordx4, coalesced 1 KB/wave).
__global__ __launch_bounds__(NTHR)
void transition_prob_kernel(const float* __restrict__ adstock,
                            const float* __restrict__ mu,
                            const float* __restrict__ beta,
                            const float* __restrict__ init_prob,
                            const float* __restrict__ click_prob,
                            float* __restrict__ out)
{
    __shared__ float sb0[N_CAMP];
    __shared__ float sb1[N_CAMP];
    __shared__ float sb2[N_CAMP];
    __shared__ float smu[3];

    const int tid = threadIdx.x;

    if (tid < 3 * N_CAMP) {
        const int c = tid / 3;
        const int k = tid % 3;
        const float v = beta[tid];
        if (k == 0) sb0[c] = v;
        else if (k == 1) sb1[c] = v;
        else sb2[c] = v;
    }
    if (tid < 3) smu[tid] = mu[tid];
    __syncthreads();

    const int bb = tid / THR_PER_B;          // 0..3
    const int q  = tid % THR_PER_B;          // 0..95; active if q < 92
    const int b  = blockIdx.x * B_PER_BLK + bb;

    // Fold the two scalar sigmoids into this kernel (one otherwise-idle thread).
    if (blockIdx.x == 0 && tid == THR_PER_B - 1) {   // bb=0, q=95 (inactive)
        const size_t base = (size_t)BATCH * DAYS * 9;
        out[base + 0] = 1.0f / (1.0f + expf(-init_prob[0]));
        out[base + 1] = 1.0f / (1.0f + expf(-click_prob[0]));
    }

    const float m0 = smu[0], m1 = smu[1], m2 = smu[2];

    if (q < 91) {
        // days 4q .. 4q+3, elements 4q+1 .. 4q+4 of each campaign row
        const float* arow = adstock + (size_t)b * (N_CAMP * ROW) + (4 * q + 1);

        float o1x = 0.f, o1y = 0.f, o1z = 0.f, o1w = 0.f;
        float o2x = 0.f, o2y = 0.f, o2z = 0.f, o2w = 0.f;
        float o3x = 0.f, o3y = 0.f, o3z = 0.f, o3w = 0.f;

#pragma unroll 10
        for (int c = 0; c < N_CAMP; ++c) {
            const float4 a = *reinterpret_cast<const float4*>(arow + (size_t)c * ROW);
            const float b0 = sb0[c], b1 = sb1[c], b2 = sb2[c];
            o1x = fmaf(a.x, b0, o1x); o1y = fmaf(a.y, b0, o1y);
            o1z = fmaf(a.z, b0, o1z); o1w = fmaf(a.w, b0, o1w);
            o2x = fmaf(a.x, b1, o2x); o2y = fmaf(a.y, b1, o2y);
            o2z = fmaf(a.z, b1, o2z); o2w = fmaf(a.w, b1, o2w);
            o3x = fmaf(a.x, b2, o3x); o3y = fmaf(a.y, b2, o3y);
            o3z = fmaf(a.z, b2, o3z); o3w = fmaf(a.w, b2, o3w);
        }

        const float O1[4] = {o1x, o1y, o1z, o1w};
        const float O2[4] = {o2x, o2y, o2z, o2w};
        const float O3[4] = {o3x, o3y, o3z, o3w};

#pragma unroll
        for (int j = 0; j < 4; ++j) {
            const int d = 4 * q + j;
            const float e1 = expf(m0 + O1[j]);
            const float e2 = expf(m1 + O2[j]);
            const float e3 = expf(m2 + O3[j]);
            const float inv0 = 1.0f / (1.0f + e1);
            const float inv1 = 1.0f / (1.0f + e2 + e3);

            float* qo = out + ((size_t)b * DAYS + d) * 9;
            qo[0] = fmaxf(inv0,      BASIS);
            qo[1] = fmaxf(e1 * inv0, BASIS);
            qo[2] = BASIS;
            qo[3] = fmaxf(e2 * inv1, BASIS);
            qo[4] = fmaxf(inv1,      BASIS);
            qo[5] = fmaxf(e3 * inv1, BASIS);
            qo[6] = BASIS;
            qo[7] = BASIS;
            qo[8] = 1.0f;
        }
    } else if (q == 91) {
        // day 364 only (element 365) -- scalar to avoid OOB past row end
        const float* arow = adstock + (size_t)b * (N_CAMP * ROW) + 365;
        float o1 = 0.f, o2 = 0.f, o3 = 0.f;
#pragma unroll 10
        for (int c = 0; c < N_CAMP; ++c) {
            const float a = arow[(size_t)c * ROW];
            o1 = fmaf(a, sb0[c], o1);
            o2 = fmaf(a, sb1[c], o2);
            o3 = fmaf(a, sb2[c], o3);
        }
        const float e1 = expf(m0 + o1);
        const float e2 = expf(m1 + o2);
        const float e3 = expf(m2 + o3);
        const float inv0 = 1.0f / (1.0f + e1);
        const float inv1 = 1.0f / (1.0f + e2 + e3);

        float* qo = out + ((size_t)b * DAYS + 364) * 9;
        qo[0] = fmaxf(inv0,      BASIS);
        qo[1] = fmaxf(e1 * inv0, BASIS);
        qo[2] = BASIS;
        qo[3] = fmaxf(e2 * inv1, BASIS);
        qo[4] = fmaxf(inv1,      BASIS);
        qo[5] = fmaxf(e3 * inv1, BASIS);
        qo[6] = BASIS;
        qo[7] = BASIS;
        qo[8] = 1.0f;
    }
}

extern "C" void kernel_launch(void* const* d_in, const int* in_sizes, int n_in,
                              void* d_out, int out_size, void* d_ws, size_t ws_size,
                              hipStream_t stream)
{
    const float* adstock    = (const float*)d_in[0];
    const float* mu         = (const float*)d_in[1];
    const float* beta       = (const float*)d_in[2];
    const float* init_prob  = (const float*)d_in[3];
    const float* click_prob = (const float*)d_in[4];
    float* out = (float*)d_out;

    transition_prob_kernel<<<dim3(BATCH / B_PER_BLK), dim3(NTHR), 0, stream>>>(
        adstock, mu, beta, init_prob, click_prob, out);
}

// Round 4
// 77.270 us; speedup vs baseline: 1.1019x; 1.1019x over previous
//
#include <hip/hip_runtime.h>

#define N_CAMP 50
#define DAYS   365
#define ROW    366          // DAYS+1 (even -> float2 alignment preserved across c)
#define ROW2   (ROW / 2)    // 183 float2s per row
#define BASIS  1e-10f
#define BATCH  4096
#define NTHR   192

// One block per batch element b. Thread q (q < 183) handles up to 2 days via
// ONE aligned float2 load per campaign: elements {2q, 2q+1} of each row.
//   q = 0:  element 1 -> day 0          (element 0 is the unused adstock[:,:,0])
//   q >= 1: elements {2q, 2q+1} -> days {2q-1, 2q}
// Wave reads 512 B contiguous per campaign iteration (8 B/lane, aligned).
__global__ __launch_bounds__(NTHR)
void transition_prob_kernel(const float* __restrict__ adstock,
                            const float* __restrict__ mu,
                            const float* __restrict__ beta,
                            const float* __restrict__ init_prob,
                            const float* __restrict__ click_prob,
                            float* __restrict__ out)
{
    __shared__ float sb0[N_CAMP];
    __shared__ float sb1[N_CAMP];
    __shared__ float sb2[N_CAMP];
    __shared__ float smu[3];

    const int tid = threadIdx.x;
    const int b   = blockIdx.x;

    if (tid < 3 * N_CAMP) {
        const int c = tid / 3;
        const int k = tid % 3;
        const float v = beta[tid];
        if (k == 0) sb0[c] = v;
        else if (k == 1) sb1[c] = v;
        else sb2[c] = v;
    }
    if (tid < 3) smu[tid] = mu[tid];
    __syncthreads();

    // Fold the two scalar sigmoids into this kernel (an inactive thread).
    if (b == 0 && tid == NTHR - 1) {
        const size_t base = (size_t)BATCH * DAYS * 9;
        out[base + 0] = 1.0f / (1.0f + __expf(-init_prob[0]));
        out[base + 1] = 1.0f / (1.0f + __expf(-click_prob[0]));
    }

    const int q = tid;
    if (q < ROW2) {
        const float2* arow = reinterpret_cast<const float2*>(
            adstock + (size_t)b * (N_CAMP * ROW)) + q;

        const float m0 = smu[0], m1 = smu[1], m2 = smu[2];

        float o1x = 0.f, o1y = 0.f;
        float o2x = 0.f, o2y = 0.f;
        float o3x = 0.f, o3y = 0.f;

#pragma unroll 10
        for (int c = 0; c < N_CAMP; ++c) {
            const float2 a = arow[c * ROW2];
            const float b0 = sb0[c], b1 = sb1[c], b2 = sb2[c];
            o1x = fmaf(a.x, b0, o1x); o1y = fmaf(a.y, b0, o1y);
            o2x = fmaf(a.x, b1, o2x); o2y = fmaf(a.y, b1, o2y);
            o3x = fmaf(a.x, b2, o3x); o3y = fmaf(a.y, b2, o3y);
        }

        // --- day B = 2q (from .y) : always valid ---
        {
            const float e1 = __expf(m0 + o1y);
            const float e2 = __expf(m1 + o2y);
            const float e3 = __expf(m2 + o3y);
            const float inv0 = __frcp_rn(1.0f + e1);
            const float inv1 = __frcp_rn(1.0f + e2 + e3);
            float* qo = out + ((size_t)b * DAYS + 2 * q) * 9;
            qo[0] = fmaxf(inv0,      BASIS);
            qo[1] = fmaxf(e1 * inv0, BASIS);
            qo[2] = BASIS;
            qo[3] = fmaxf(e2 * inv1, BASIS);
            qo[4] = fmaxf(inv1,      BASIS);
            qo[5] = fmaxf(e3 * inv1, BASIS);
            qo[6] = BASIS;
            qo[7] = BASIS;
            qo[8] = 1.0f;
        }
        // --- day A = 2q-1 (from .x) : valid for q >= 1 ---
        if (q >= 1) {
            const float e1 = __expf(m0 + o1x);
            const float e2 = __expf(m1 + o2x);
            const float e3 = __expf(m2 + o3x);
            const float inv0 = __frcp_rn(1.0f + e1);
            const float inv1 = __frcp_rn(1.0f + e2 + e3);
            float* qo = out + ((size_t)b * DAYS + 2 * q - 1) * 9;
            qo[0] = fmaxf(inv0,      BASIS);
            qo[1] = fmaxf(e1 * inv0, BASIS);
            qo[2] = BASIS;
            qo[3] = fmaxf(e2 * inv1, BASIS);
            qo[4] = fmaxf(inv1,      BASIS);
            qo[5] = fmaxf(e3 * inv1, BASIS);
            qo[6] = BASIS;
            qo[7] = BASIS;
            qo[8] = 1.0f;
        }
    }
}

extern "C" void kernel_launch(void* const* d_in, const int* in_sizes, int n_in,
                              void* d_out, int out_size, void* d_ws, size_t ws_size,
                              hipStream_t stream)
{
    const float* adstock    = (const float*)d_in[0];
    const float* mu         = (const float*)d_in[1];
    const float* beta       = (const float*)d_in[2];
    const float* init_prob  = (const float*)d_in[3];
    const float* click_prob = (const float*)d_in[4];
    float* out = (float*)d_out;

    transition_prob_kernel<<<dim3(BATCH), dim3(NTHR), 0, stream>>>(
        adstock, mu, beta, init_prob, click_prob, out);
}